// Round 1
// baseline (1310.280 us; speedup 1.0000x reference)
//
#include <hip/hip_runtime.h>
#include <math.h>

#define NCLS 100
#define D 64
#define ACC_FLOATS (NCLS * D * 2 + NCLS)   // 12900 floats = 51.6 KB
#define BLK1 256
#define GRID1 768
#define UNROLL 8

// ---------------- Kernel 1: segmented sum / sumsq / count ----------------
__global__ __launch_bounds__(BLK1) void seg_stats_kernel(
    const float* __restrict__ pred, const int* __restrict__ idx,
    float* __restrict__ gacc, int nrows)
{
    __shared__ float sm[ACC_FLOATS];
    for (int i = threadIdx.x; i < ACC_FLOATS; i += BLK1) sm[i] = 0.0f;
    __syncthreads();

    float* sSum = sm;                 // [NCLS*D]
    float* sSq  = sm + NCLS * D;      // [NCLS*D]
    float* sCnt = sm + 2 * NCLS * D;  // [NCLS]

    const int lane = threadIdx.x & 63;
    int wid = (int)((blockIdx.x * blockDim.x + threadIdx.x) >> 6);
    wid = __builtin_amdgcn_readfirstlane(wid);
    const int nwaves = (GRID1 * BLK1) >> 6;

    const int chunk = (nrows + nwaves - 1) / nwaves;
    long long start = (long long)wid * chunk;
    long long end   = start + chunk;
    if (end > nrows) end = nrows;
    if (start > end) start = end;

    long long r = start;
    for (; r + UNROLL <= end; r += UNROLL) {
        int   cc[UNROLL];
        float vv[UNROLL];
        #pragma unroll
        for (int u = 0; u < UNROLL; ++u) cc[u] = idx[r + u];   // wave-uniform -> s_load
        #pragma unroll
        for (int u = 0; u < UNROLL; ++u)
            vv[u] = pred[(size_t)(r + u) * D + lane];          // coalesced 256B
        #pragma unroll
        for (int u = 0; u < UNROLL; ++u) {
            atomicAdd(&sSum[cc[u] * D + lane], vv[u]);
            atomicAdd(&sSq [cc[u] * D + lane], vv[u] * vv[u]);
        }
        if (lane == 0) {
            #pragma unroll
            for (int u = 0; u < UNROLL; ++u) atomicAdd(&sCnt[cc[u]], 1.0f);
        }
    }
    for (; r < end; ++r) {
        int c = idx[r];
        float v = pred[(size_t)r * D + lane];
        atomicAdd(&sSum[c * D + lane], v);
        atomicAdd(&sSq [c * D + lane], v * v);
        if (lane == 0) atomicAdd(&sCnt[c], 1.0f);
    }
    __syncthreads();

    for (int i = threadIdx.x; i < ACC_FLOATS; i += BLK1)
        atomicAdd(&gacc[i], sm[i]);
}

// ---------------- Kernel 2: finalize (means/std/cov/pair distances) ------
#define MSTR 68   // padded stride: 16B-aligned, breaks bank alignment

__global__ __launch_bounds__(1024) void finalize_kernel(
    const float* __restrict__ gacc, float* __restrict__ out)
{
    __shared__ float mean_s[NCLS * MSTR];
    __shared__ float colstd[D];
    __shared__ float norms[NCLS];
    __shared__ float redSum[16], redMin[16];
    __shared__ float s_cov;

    const float* gSum = gacc;
    const float* gSq  = gacc + NCLS * D;
    const float* gCnt = gacc + 2 * NCLS * D;

    for (int d = threadIdx.x; d < D; d += 1024) colstd[d] = 0.0f;
    __syncthreads();

    // mean, std, colstd accumulation
    for (int i = threadIdx.x; i < NCLS * D; i += 1024) {
        int c = i >> 6, d = i & 63;
        float cnt = gCnt[c];
        float m   = gSum[i] / cnt;
        float var = (gSq[i] - cnt * m * m) / (cnt - 1.0f);
        float sd  = sqrtf(fmaxf(var, 0.0f));
        mean_s[c * MSTR + d] = m;
        atomicAdd(&colstd[d], sd);
    }
    __syncthreads();

    // cov = sum_d (colstd[d]^2) / C   (wave 0 only)
    if (threadIdx.x < 64) {
        float v = colstd[threadIdx.x];
        v = v * v;
        for (int o = 32; o; o >>= 1) v += __shfl_down(v, o);
        if (threadIdx.x == 0) s_cov = v / (float)NCLS;
    }

    // norms[c] = |mean_c|^2
    for (int c = threadIdx.x; c < NCLS; c += 1024) {
        const float4* mp = (const float4*)&mean_s[c * MSTR];
        float n = 0.0f;
        #pragma unroll
        for (int d4 = 0; d4 < D / 4; ++d4) {
            float4 a = mp[d4];
            n += a.x * a.x + a.y * a.y + a.z * a.z + a.w * a.w;
        }
        norms[c] = n;
    }
    __syncthreads();

    // pair distances over lower triangle (i>j), 4950 pairs
    const int n_pairs = NCLS * (NCLS - 1) / 2;
    float lsum = 0.0f, lmin = INFINITY;
    for (int p = threadIdx.x; p < n_pairs; p += 1024) {
        int i = (int)((1.0f + sqrtf(1.0f + 8.0f * (float)p)) * 0.5f);
        while (i * (i - 1) / 2 > p) --i;
        while ((i + 1) * i / 2 <= p) ++i;
        int j = p - i * (i - 1) / 2;

        const float4* mi = (const float4*)&mean_s[i * MSTR];
        const float4* mj = (const float4*)&mean_s[j * MSTR];
        float dot = 0.0f;
        #pragma unroll
        for (int d4 = 0; d4 < D / 4; ++d4) {
            float4 a = mi[d4], b = mj[d4];
            dot += a.x * b.x + a.y * b.y + a.z * b.z + a.w * b.w;
        }
        float dist = norms[i] + norms[j] - 2.0f * dot;
        lsum += dist;
        lmin = fminf(lmin, dist);
    }

    // block reduce (16 waves)
    for (int o = 32; o; o >>= 1) {
        lsum += __shfl_down(lsum, o);
        lmin = fminf(lmin, __shfl_down(lmin, o));
    }
    int w = threadIdx.x >> 6;
    if ((threadIdx.x & 63) == 0) { redSum[w] = lsum; redMin[w] = lmin; }
    __syncthreads();

    if (threadIdx.x == 0) {
        float S = 0.0f, M = INFINITY;
        for (int k = 0; k < 16; ++k) { S += redSum[k]; M = fminf(M, redMin[k]); }
        float md  = S / (float)n_pairs;
        float cov = s_cov;
        float e   = 8.0f - md;
        float loss = 1.0f * cov + 0.1f * e * e;   // C_COEF = 0
        out[0] = loss;
        out[1] = md;
        out[2] = M;
        out[3] = cov;
    }
}

extern "C" void kernel_launch(void* const* d_in, const int* in_sizes, int n_in,
                              void* d_out, int out_size, void* d_ws, size_t ws_size,
                              hipStream_t stream) {
    const float* pred = (const float*)d_in[0];
    const int*   gidx = (const int*)d_in[1];
    float* out  = (float*)d_out;
    float* gacc = (float*)d_ws;
    int nrows = in_sizes[1];   // 2,000,000 rows

    hipMemsetAsync(gacc, 0, ACC_FLOATS * sizeof(float), stream);
    seg_stats_kernel<<<GRID1, BLK1, 0, stream>>>(pred, gidx, gacc, nrows);
    finalize_kernel<<<1, 1024, 0, stream>>>(gacc, out);
}